// Round 1
// baseline (798.358 us; speedup 1.0000x reference)
//
#include <hip/hip_runtime.h>
#include <hip/hip_bf16.h>
#include <stdint.h>

#define B_ 8192
#define D_ 1024
#define H_ 4096
#define O_ 1024
#define E_ 8

typedef __attribute__((ext_vector_type(8))) short bf16x8;
typedef __attribute__((ext_vector_type(4))) float f32x4;

__device__ __forceinline__ ushort f2bf(float f) {
  uint32_t u = __builtin_bit_cast(uint32_t, f);
  uint32_t r = (u + 0x7FFFu + ((u >> 16) & 1u)) >> 16;
  return (ushort)r;
}
__device__ __forceinline__ float bf2f(ushort u) {
  uint32_t v = ((uint32_t)u) << 16;
  return __builtin_bit_cast(float, v);
}

__device__ __forceinline__ void gload_lds16(const ushort* g, ushort* l) {
  __builtin_amdgcn_global_load_lds(
      (__attribute__((address_space(1))) void*)g,
      (__attribute__((address_space(3))) void*)l, 16, 0, 0);
}

// ---------------- x fp32 -> bf16 ----------------
__global__ void cvt_x_k(const float* __restrict__ x, ushort* __restrict__ xb) {
  int i = blockIdx.x * 256 + threadIdx.x;            // over B*D/4
  float4 v = ((const float4*)x)[i];
  ushort4 r;
  r.x = f2bf(v.x); r.y = f2bf(v.y); r.z = f2bf(v.z); r.w = f2bf(v.w);
  ((ushort4*)xb)[i] = r;
}

// ------------- per-expert transpose + cvt: in [E][R][C] f32 -> out [E][C][R] bf16 -------------
__global__ void transpose_cvt(const float* __restrict__ in, ushort* __restrict__ out,
                              int R, int C) {
  __shared__ ushort tile[64][66];
  int h0 = blockIdx.x * 64, d0 = blockIdx.y * 64;
  size_t eoff = (size_t)blockIdx.z * R * C;
  int t = threadIdx.x;
  int a = t & 63, q = t >> 6;
#pragma unroll
  for (int i = 0; i < 16; ++i) {
    int dl = q * 16 + i;
    tile[dl][a] = f2bf(in[eoff + (size_t)(d0 + dl) * C + h0 + a]);
  }
  __syncthreads();
#pragma unroll
  for (int i = 0; i < 16; ++i) {
    int hh = q * 16 + i;
    out[eoff + (size_t)(h0 + hh) * R + d0 + a] = tile[a][hh];
  }
}

// ---------------- gating: logits, top-2, softmax, routing prep ----------------
__global__ void gating_k(const float* __restrict__ x, const float* __restrict__ Wg,
                         const float* __restrict__ bg, float* __restrict__ gates,
                         float* __restrict__ topi, int* __restrict__ exp_a,
                         float* __restrict__ gate_a, int* __restrict__ counts) {
  int row = blockIdx.x * 4 + (threadIdx.x >> 6);
  int lane = threadIdx.x & 63;
  const float* xr = x + (size_t)row * D_;
  float acc[8];
#pragma unroll
  for (int e = 0; e < 8; ++e) acc[e] = 0.f;
  for (int j = 0; j < 16; ++j) {
    int d = j * 64 + lane;
    float xv = xr[d];
    const float4* wp = (const float4*)(Wg + d * 8);
    float4 w0 = wp[0], w1 = wp[1];
    acc[0] = fmaf(xv, w0.x, acc[0]); acc[1] = fmaf(xv, w0.y, acc[1]);
    acc[2] = fmaf(xv, w0.z, acc[2]); acc[3] = fmaf(xv, w0.w, acc[3]);
    acc[4] = fmaf(xv, w1.x, acc[4]); acc[5] = fmaf(xv, w1.y, acc[5]);
    acc[6] = fmaf(xv, w1.z, acc[6]); acc[7] = fmaf(xv, w1.w, acc[7]);
  }
#pragma unroll
  for (int e = 0; e < 8; ++e) {
#pragma unroll
    for (int off = 32; off; off >>= 1) acc[e] += __shfl_xor(acc[e], off);
  }
  if (lane == 0) {
    float v0 = -1e30f, v1 = -1e30f; int i0 = 0, i1 = 0;
#pragma unroll
    for (int e = 0; e < 8; ++e) {
      float ve = acc[e] + bg[e];
      if (ve > v0)      { v1 = v0; i1 = i0; v0 = ve; i0 = e; }
      else if (ve > v1) { v1 = ve; i1 = e; }
    }
    float t = expf(v1 - v0);
    float g0 = 1.f / (1.f + t), g1 = t / (1.f + t);
    gates[row * 8 + i0] = g0;
    gates[row * 8 + i1] = g1;
    topi[row * 2 + 0] = (float)i0;
    topi[row * 2 + 1] = (float)i1;
    exp_a[row * 2 + 0] = i0;
    exp_a[row * 2 + 1] = i1;
    gate_a[row * 2 + 0] = g0;
    gate_a[row * 2 + 1] = g1;
    atomicAdd(&counts[i0], 1);
    atomicAdd(&counts[i1], 1);
  }
}

__global__ void prefix_k(const int* __restrict__ counts, int* __restrict__ offs,
                         int* __restrict__ cursors) {
  if (threadIdx.x == 0) {
    int s = 0;
    for (int e = 0; e < 8; ++e) { offs[e] = s; cursors[e] = s; s += counts[e]; }
  }
}

__global__ void scatter_k(const int* __restrict__ exp_a, int* __restrict__ cursors,
                          int* __restrict__ rows, int* __restrict__ slot_of) {
  int a = blockIdx.x * 256 + threadIdx.x;            // 0..16383
  int e = exp_a[a];
  int slot = atomicAdd(&cursors[e], 1);
  rows[slot] = a >> 1;
  slot_of[a] = slot;
}

// ---------------- grouped expert GEMM (bf16 MFMA, 128x128x64, swizzled LDS) ----------------
template <int LAYER>
__global__ __launch_bounds__(256, 2)
void moe_gemm(const ushort* __restrict__ Abase, const ushort* __restrict__ Bbase,
              const float* __restrict__ bias, ushort* __restrict__ hout,
              float* __restrict__ part, const int* __restrict__ rows,
              const int* __restrict__ counts, const int* __restrict__ offs) {
  constexpr int KD = (LAYER == 1) ? D_ : H_;   // K dim
  constexpr int ND = (LAYER == 1) ? H_ : O_;   // N dim (rows of Bt)
  int e = blockIdx.z;
  int cnt = counts[e];
  int m0 = blockIdx.y * 128;
  if (m0 >= cnt) return;
  int n0 = blockIdx.x * 128;
  int off = offs[e];

  __shared__ __align__(16) ushort sA[128 * 64];
  __shared__ __align__(16) ushort sB[128 * 64];

  int tid = threadIdx.x;
  int wid = tid >> 6, lane = tid & 63;
  int wr = wid >> 1, wc = wid & 1;

  // --- staging source pointers (inverse-swizzled per-lane source, linear LDS dest) ---
  int xorc = ((lane & 7) ^ (lane >> 3)) << 3;  // element offset within 64-elem k-row
  const ushort* pA[4];
  const ushort* pB[4];
#pragma unroll
  for (int i = 0; i < 4; ++i) {
    int rit = wid * 32 + i * 8 + (lane >> 3);  // row in tile 0..127
    int slot = m0 + rit; slot = (slot < cnt) ? slot : (cnt - 1);
    size_t arow;
    if (LAYER == 1) arow = (size_t)rows[off + slot];
    else            arow = (size_t)(off + slot);
    pA[i] = Abase + arow * KD + xorc;
    int brow = n0 + rit;
    pB[i] = Bbase + ((size_t)e * ND + brow) * KD + xorc;
  }

  f32x4 acc[4][4];
  f32x4 z = {0.f, 0.f, 0.f, 0.f};
#pragma unroll
  for (int m = 0; m < 4; ++m)
#pragma unroll
    for (int n = 0; n < 4; ++n) acc[m][n] = z;

  int lrow = lane & 15;
  int lkb = (lane >> 4) << 4;        // byte offset of k-group within 128B row
  int swz = (lane & 7) << 4;

  for (int kt = 0; kt < KD / 64; ++kt) {
#pragma unroll
    for (int i = 0; i < 4; ++i) {
      gload_lds16(pA[i], &sA[(wid * 4 + i) * 512]);
      gload_lds16(pB[i], &sB[(wid * 4 + i) * 512]);
      pA[i] += 64; pB[i] += 64;
    }
    __syncthreads();
#pragma unroll
    for (int ks = 0; ks < 2; ++ks) {
      bf16x8 af[4], bfr[4];
#pragma unroll
      for (int m = 0; m < 4; ++m) {
        int r = wr * 64 + m * 16 + lrow;
        int byte = r * 128 + ((ks * 64 + lkb) ^ swz);
        af[m] = *(const bf16x8*)((const char*)sA + byte);
      }
#pragma unroll
      for (int n = 0; n < 4; ++n) {
        int r = wc * 64 + n * 16 + lrow;
        int byte = r * 128 + ((ks * 64 + lkb) ^ swz);
        bfr[n] = *(const bf16x8*)((const char*)sB + byte);
      }
#pragma unroll
      for (int m = 0; m < 4; ++m)
#pragma unroll
        for (int n = 0; n < 4; ++n)
          acc[m][n] = __builtin_amdgcn_mfma_f32_16x16x32_bf16(af[m], bfr[n], acc[m][n], 0, 0, 0);
    }
    __syncthreads();
  }

  // --- epilogue: C/D layout col=lane&15, row=(lane>>4)*4+j ---
  const float* bias_e = bias + (size_t)e * ND;
  int colbase = n0 + wc * 64;
#pragma unroll
  for (int m = 0; m < 4; ++m) {
    int rl = m0 + wr * 64 + m * 16 + ((lane >> 4) << 2);
#pragma unroll
    for (int n = 0; n < 4; ++n) {
      int cg = colbase + n * 16 + (lane & 15);
      float bv = bias_e[cg];
      f32x4 a = acc[m][n];
#pragma unroll
      for (int j = 0; j < 4; ++j) {
        int r = rl + j;
        if (r < cnt) {
          float v = a[j] + bv;
          if (LAYER == 1) {
            v = fmaxf(v, 0.f);
            hout[(size_t)(off + r) * H_ + cg] = f2bf(v);
          } else {
            part[(size_t)(off + r) * O_ + cg] = v;
          }
        }
      }
    }
  }
}

// ---------------- combine: out[b] = g0*part[s0] + g1*part[s1] ----------------
__global__ void combine_k(const float* __restrict__ part, const int* __restrict__ slot_of,
                          const float* __restrict__ gate_a, float* __restrict__ out) {
  int i = blockIdx.x * 256 + threadIdx.x;  // over B*O/4
  int b = i >> 8;
  int c4 = i & 255;
  int s0 = slot_of[b * 2], s1 = slot_of[b * 2 + 1];
  float g0 = gate_a[b * 2], g1 = gate_a[b * 2 + 1];
  float4 p0 = ((const float4*)(part + (size_t)s0 * O_))[c4];
  float4 p1 = ((const float4*)(part + (size_t)s1 * O_))[c4];
  float4 r;
  r.x = g0 * p0.x + g1 * p1.x;
  r.y = g0 * p0.y + g1 * p1.y;
  r.z = g0 * p0.z + g1 * p1.z;
  r.w = g0 * p0.w + g1 * p1.w;
  ((float4*)(out + (size_t)b * O_))[c4] = r;
}

// ---------------- importance / load (deterministic fixed-tree reduce) ----------------
__global__ void importance_k(const float* __restrict__ gates, float* __restrict__ load,
                             float* __restrict__ imp) {
  int e = blockIdx.x;
  float s = 0.f;
  for (int b = threadIdx.x; b < B_; b += 256) s += gates[b * 8 + e];
  __shared__ float red[4];
#pragma unroll
  for (int off = 32; off; off >>= 1) s += __shfl_xor(s, off);
  if ((threadIdx.x & 63) == 0) red[threadIdx.x >> 6] = s;
  __syncthreads();
  if (threadIdx.x == 0) {
    float t = (red[0] + red[1]) + (red[2] + red[3]);
    imp[e] = t;
    load[e] = t * (1.f / (float)B_);
  }
}

extern "C" void kernel_launch(void* const* d_in, const int* in_sizes, int n_in,
                              void* d_out, int out_size, void* d_ws, size_t ws_size,
                              hipStream_t stream) {
  const float* x  = (const float*)d_in[0];
  const float* Wg = (const float*)d_in[1];
  const float* bg = (const float*)d_in[2];
  const float* W1 = (const float*)d_in[3];
  const float* b1 = (const float*)d_in[4];
  const float* W2 = (const float*)d_in[5];
  const float* b2 = (const float*)d_in[6];

  float* out = (float*)d_out;
  float* out_y     = out;                 // [B,O]  8388608
  float* out_gates = out + 8388608;       // [B,E]  65536
  float* out_load  = out + 8454144;       // [E]    8
  float* out_imp   = out + 8454152;       // [E]    8
  float* out_topi  = out + 8454160;       // [B,K]  16384 (as float)

  char* w = (char*)d_ws;
  ushort* x_bf    = (ushort*)(w);                      // 16,777,216 B
  ushort* w1t     = (ushort*)(w + 16777216);           // 67,108,864 B  [E][H][D]
  ushort* w2t     = (ushort*)(w + 83886080);           // 67,108,864 B  [E][O][H]
  ushort* h_buf   = (ushort*)(w + 150994944);          // 134,217,728 B [16384][H]
  float*  part    = (float*)(w + 285212672);           // 67,108,864 B  [16384][O]
  int*    rows    = (int*)(w + 352321536);             // 65536 B
  int*    slot_of = (int*)(w + 352387072);             // 65536 B
  int*    exp_a   = (int*)(w + 352452608);             // 65536 B
  float*  gate_a  = (float*)(w + 352518144);           // 65536 B
  int*    counts  = (int*)(w + 352583680);             // 32 B
  int*    offs    = (int*)(w + 352583712);             // 32 B
  int*    cursors = (int*)(w + 352583744);             // 32 B

  (void)in_sizes; (void)n_in; (void)out_size; (void)ws_size;

  hipMemsetAsync(out_gates, 0, 65536 * sizeof(float), stream);
  hipMemsetAsync(counts, 0, 96, stream);

  cvt_x_k<<<B_ * D_ / 4 / 256, 256, 0, stream>>>(x, x_bf);
  transpose_cvt<<<dim3(H_ / 64, D_ / 64, E_), 256, 0, stream>>>(W1, w1t, D_, H_);
  transpose_cvt<<<dim3(O_ / 64, H_ / 64, E_), 256, 0, stream>>>(W2, w2t, H_, O_);

  gating_k<<<B_ / 4, 256, 0, stream>>>(x, Wg, bg, out_gates, out_topi, exp_a, gate_a, counts);
  prefix_k<<<1, 64, 0, stream>>>(counts, offs, cursors);
  scatter_k<<<64, 256, 0, stream>>>(exp_a, cursors, rows, slot_of);

  moe_gemm<1><<<dim3(H_ / 128, 64, E_), 256, 0, stream>>>(x_bf, w1t, b1, h_buf, part,
                                                          rows, counts, offs);
  moe_gemm<2><<<dim3(O_ / 128, 64, E_), 256, 0, stream>>>(h_buf, w2t, b2, h_buf, part,
                                                          rows, counts, offs);

  combine_k<<<B_ * O_ / 4 / 256, 256, 0, stream>>>(part, slot_of, gate_a, out_y);
  importance_k<<<E_, 256, 0, stream>>>(out_gates, out_load, out_imp);
}